// Round 6
// baseline (224.623 us; speedup 1.0000x reference)
//
#include <hip/hip_runtime.h>
#include <hip/hip_bf16.h>

#define NEG_SLOPE 0.2f

__device__ __forceinline__ unsigned short f2bf(float f) {
    unsigned int u = __float_as_uint(f);
    u += 0x7FFFu + ((u >> 16) & 1u);   // RNE
    return (unsigned short)(u >> 16);
}

// ---------------- CSR build ----------------

__global__ void zero_kernel(int* __restrict__ p, int count) {
    int i = blockIdx.x * blockDim.x + threadIdx.x;
    if (i < count) p[i] = 0;
}

__global__ void count_kernel(const int* __restrict__ ei, int e, int n, int* __restrict__ cnt) {
    int i = blockIdx.x * blockDim.x + threadIdx.x;
    int total = e + n;
    if (i >= total) return;
    int dst = (i < e) ? ei[e + i] : (i - e);
    atomicAdd(&cnt[dst], 1);
}

// block b sums cnt[b*1024 .. b*1024+1023]
__global__ __launch_bounds__(256) void scanA_kernel(const int* __restrict__ cnt, int* __restrict__ bsum, int n) {
    int b = blockIdx.x, t = threadIdx.x;
    int base = b * 1024;
    int s = 0;
#pragma unroll
    for (int q = 0; q < 4; ++q) {
        int i = base + t + q * 256;
        if (i < n) s += cnt[i];
    }
    int lane = t & 63, wid = t >> 6;
#pragma unroll
    for (int off = 32; off; off >>= 1) s += __shfl_xor(s, off, 64);
    __shared__ int ws[4];
    if (lane == 0) ws[wid] = s;
    __syncthreads();
    if (t == 0) bsum[b] = ws[0] + ws[1] + ws[2] + ws[3];
}

// single wave: exclusive scan of nb block sums; writes rowptr[n]=total
__global__ __launch_bounds__(64) void scanB_kernel(const int* __restrict__ bsum, int* __restrict__ bbase,
                                                   int* __restrict__ rowptr, int nb, int n) {
    int t = threadIdx.x;
    int carry = 0;
    for (int c = 0; c < nb; c += 64) {
        int i = c + t;
        int v = (i < nb) ? bsum[i] : 0;
        int incl = v;
#pragma unroll
        for (int off = 1; off < 64; off <<= 1) {
            int u = __shfl_up(incl, off, 64);
            if (t >= off) incl += u;
        }
        if (i < nb) bbase[i] = carry + incl - v;
        carry += __shfl(incl, 63, 64);
    }
    if (t == 0) rowptr[n] = carry;
}

// block b: local exclusive scan of its 1024 cnt values + bbase[b] -> rowptr
__global__ __launch_bounds__(256) void scanC_kernel(const int* __restrict__ cnt, const int* __restrict__ bbase,
                                                    int* __restrict__ rowptr, int n) {
    int b = blockIdx.x, t = threadIdx.x;
    int idx = b * 1024 + t * 4;
    int4 v = make_int4(0, 0, 0, 0);
    if (idx + 3 < n) v = *(const int4*)(cnt + idx);
    else {
        if (idx < n)     v.x = cnt[idx];
        if (idx + 1 < n) v.y = cnt[idx + 1];
        if (idx + 2 < n) v.z = cnt[idx + 2];
        if (idx + 3 < n) v.w = cnt[idx + 3];
    }
    int s0 = v.x, s1 = s0 + v.y, s2 = s1 + v.z, s3 = s2 + v.w;
    int tot = s3;
    int lane = t & 63, wid = t >> 6;
    int incl = tot;
#pragma unroll
    for (int off = 1; off < 64; off <<= 1) {
        int u = __shfl_up(incl, off, 64);
        if (lane >= off) incl += u;
    }
    __shared__ int wtot[4];
    if (lane == 63) wtot[wid] = incl;
    __syncthreads();
    int woff = 0;
    for (int w = 0; w < wid; ++w) woff += wtot[w];
    int ex = incl - tot + woff + bbase[b];
    if (idx < n)     rowptr[idx]     = ex;
    if (idx + 1 < n) rowptr[idx + 1] = ex + s0;
    if (idx + 2 < n) rowptr[idx + 2] = ex + s1;
    if (idx + 3 < n) rowptr[idx + 3] = ex + s2;
}

__global__ void fill_kernel(const int* __restrict__ ei, int e, int n,
                            const int* __restrict__ rowptr, int* __restrict__ fillc,
                            int* __restrict__ colsrc) {
    int i = blockIdx.x * blockDim.x + threadIdx.x;
    int total = e + n;
    if (i >= total) return;
    int src, dst;
    if (i < e) { src = ei[i]; dst = ei[e + i]; }
    else       { src = i - e; dst = i - e; }
    int pos = atomicAdd(&fillc[dst], 1);
    colsrc[rowptr[dst] + pos] = src;
}

// ---------------- GEMM + fused alpha; bf16 h output ----------------
// BM=32, BN=128, BK=32, 256 threads. tx=tid&31 (cols tx*4), ty=tid>>5 (rows ty*4..+3)

template <int H>
__global__ __launch_bounds__(256) void gemm_alpha_kernel(const float* __restrict__ X,
                                                         const float* __restrict__ W,
                                                         const float* __restrict__ asrc,
                                                         const float* __restrict__ adst,
                                                         unsigned short* __restrict__ Ob,
                                                         float* __restrict__ as_out,
                                                         float* __restrict__ ad_out, int n) {
    __shared__ float sW[32][128];
    __shared__ float sX[32][36];
    int tid = threadIdx.x;
    int row0 = blockIdx.x * 32;
    int tx = tid & 31, ty = tid >> 5;
    int tx4 = tx * 4, ty4 = ty * 4;

    int xr0 = tid >> 3;            // 0..31
    int xc0 = (tid & 7) * 4;       // col within chunk

    float4 xp;
    float4 wp[4];

    auto load_chunk = [&](int kc) {
        int k0 = kc * 32;
        int gr = row0 + xr0;
        xp = make_float4(0.f, 0.f, 0.f, 0.f);
        if (gr < n) xp = *(const float4*)(X + (size_t)gr * 128 + k0 + xc0);
#pragma unroll
        for (int t = 0; t < 4; ++t) {
            int f = tid + t * 256;
            int kr = f >> 5, c4 = (f & 31) * 4;
            wp[t] = *(const float4*)(W + (size_t)(k0 + kr) * 128 + c4);
        }
    };

    float acc[4][4];
#pragma unroll
    for (int i = 0; i < 4; ++i)
#pragma unroll
        for (int j = 0; j < 4; ++j) acc[i][j] = 0.f;

    load_chunk(0);

    for (int kc = 0; kc < 4; ++kc) {
        __syncthreads();
        *(float4*)&sX[xr0][xc0] = xp;
#pragma unroll
        for (int t = 0; t < 4; ++t) {
            int f = tid + t * 256;
            int kr = f >> 5, c4 = (f & 31) * 4;
            *(float4*)&sW[kr][c4] = wp[t];
        }
        __syncthreads();
        if (kc < 3) load_chunk(kc + 1);

#pragma unroll
        for (int k4 = 0; k4 < 32; k4 += 4) {
            float4 xr_[4];
#pragma unroll
            for (int i = 0; i < 4; ++i) xr_[i] = *(const float4*)&sX[ty4 + i][k4];
#pragma unroll
            for (int kk = 0; kk < 4; ++kk) {
                float4 w0 = *(const float4*)&sW[k4 + kk][tx4];
#pragma unroll
                for (int i = 0; i < 4; ++i) {
                    float xv = ((const float*)&xr_[i])[kk];
                    acc[i][0] += xv * w0.x; acc[i][1] += xv * w0.y;
                    acc[i][2] += xv * w0.z; acc[i][3] += xv * w0.w;
                }
            }
        }
    }

    float av[4], dv[4];
#pragma unroll
    for (int j = 0; j < 4; ++j) {
        av[j] = asrc[tx4 + j];
        dv[j] = adst[tx4 + j];
    }

#pragma unroll
    for (int i = 0; i < 4; ++i) {
        int gr = row0 + ty4 + i;
        bool ok = gr < n;
        if (ok) {
            ushort4 o;
            o.x = f2bf(acc[i][0]); o.y = f2bf(acc[i][1]);
            o.z = f2bf(acc[i][2]); o.w = f2bf(acc[i][3]);
            *(ushort4*)(Ob + (size_t)gr * 128 + tx4) = o;
        }
        float ps = 0.f, pd = 0.f;
#pragma unroll
        for (int j = 0; j < 4; ++j) { ps += acc[i][j] * av[j]; pd += acc[i][j] * dv[j]; }
        if (H == 8) {
            // head of cols tx*4..tx*4+3 is tx>>2; reduce over tx&3 group
#pragma unroll
            for (int off = 1; off < 4; off <<= 1) {
                ps += __shfl_xor(ps, off, 64); pd += __shfl_xor(pd, off, 64);
            }
            if (ok && (tx & 3) == 0) {
                int h0 = tx >> 2;
                as_out[(size_t)gr * 8 + h0] = ps;
                ad_out[(size_t)gr * 8 + h0] = pd;
            }
        } else {
            // reduce over all 32 tx lanes (within 32-lane half-wave)
#pragma unroll
            for (int off = 1; off < 32; off <<= 1) {
                ps += __shfl_xor(ps, off, 64); pd += __shfl_xor(pd, off, 64);
            }
            if (ok && tx == 0) { as_out[gr] = ps; ad_out[gr] = pd; }
        }
    }
}

// ---------------- single-pass aggregation, bf16 gather ----------------
// wave per node; slot = lane>>4 (4 edges in flight), cl = lane&15 (8 channels = 16 B/lane)

template <int H>
__global__ __launch_bounds__(256) void agg_kernel(const int* __restrict__ rowptr,
                                                  const int* __restrict__ colsrc,
                                                  const unsigned short* __restrict__ hb,
                                                  const float* __restrict__ as,
                                                  const float* __restrict__ ad,
                                                  const float* __restrict__ bias,
                                                  float* __restrict__ out, int n, int applyElu) {
    int node = blockIdx.x * 4 + (threadIdx.x >> 6);
    int lane = threadIdx.x & 63;
    if (node >= n) return;
    int beg = rowptr[node];
    int end = rowptr[node + 1];

    int slot = lane >> 4;
    int cl = lane & 15;
    int head = (H == 8) ? (cl >> 1) : 0;
    float adh = ad[(size_t)node * H + head];

    float acc[8];
#pragma unroll
    for (int c = 0; c < 8; ++c) acc[c] = 0.f;
    float den = 0.f;

#pragma unroll 2
    for (int i = beg + slot; i < end; i += 4) {
        int s = colsrc[i];
        float ev = as[(size_t)s * H + head] + adh;
        ev = (ev > 0.f) ? ev : NEG_SLOPE * ev;
        float w = __expf(ev);
        den += w;
        uint4 a = *(const uint4*)(hb + (size_t)s * 128 + cl * 8);
        unsigned int u[4] = {a.x, a.y, a.z, a.w};
#pragma unroll
        for (int k = 0; k < 4; ++k) {
            float lo = __uint_as_float(u[k] << 16);
            float hi = __uint_as_float(u[k] & 0xffff0000u);
            acc[2 * k]     += w * lo;
            acc[2 * k + 1] += w * hi;
        }
    }

#pragma unroll
    for (int off = 16; off <= 32; off <<= 1) {
        den += __shfl_xor(den, off, 64);
#pragma unroll
        for (int c = 0; c < 8; ++c) acc[c] += __shfl_xor(acc[c], off, 64);
    }

    if (slot == 0) {
        float inv = 1.0f / den;
        float4 r[2];
#pragma unroll
        for (int q = 0; q < 2; ++q) {
            float4 bb = ((const float4*)bias)[cl * 2 + q];
            r[q].x = acc[4 * q]     * inv + bb.x;
            r[q].y = acc[4 * q + 1] * inv + bb.y;
            r[q].z = acc[4 * q + 2] * inv + bb.z;
            r[q].w = acc[4 * q + 3] * inv + bb.w;
            if (applyElu) {
                r[q].x = (r[q].x > 0.f) ? r[q].x : expm1f(r[q].x);
                r[q].y = (r[q].y > 0.f) ? r[q].y : expm1f(r[q].y);
                r[q].z = (r[q].z > 0.f) ? r[q].z : expm1f(r[q].z);
                r[q].w = (r[q].w > 0.f) ? r[q].w : expm1f(r[q].w);
            }
            ((float4*)(out + (size_t)node * 128 + cl * 8))[q] = r[q];
        }
    }
}

// ---------------- launch ----------------

extern "C" void kernel_launch(void* const* d_in, const int* in_sizes, int n_in,
                              void* d_out, int out_size, void* d_ws, size_t ws_size,
                              hipStream_t stream) {
    const float* x    = (const float*)d_in[0];
    const int*   ei   = (const int*)d_in[1];
    const float* W1   = (const float*)d_in[2];
    const float* a_s1 = (const float*)d_in[3];
    const float* a_d1 = (const float*)d_in[4];
    const float* b1   = (const float*)d_in[5];
    const float* W2   = (const float*)d_in[6];
    const float* a_s2 = (const float*)d_in[7];
    const float* a_d2 = (const float*)d_in[8];
    const float* b2   = (const float*)d_in[9];

    const int n  = in_sizes[0] / 128;
    const int e  = in_sizes[1] / 2;
    const int en = e + n;
    const int nb = (n + 1023) / 1024;

    char* ws = (char*)d_ws;
    size_t off = 0;
    auto alloc = [&](size_t bytes) -> void* {
        void* p = ws + off;
        off += (bytes + 255) & ~(size_t)255;
        return p;
    };
    unsigned short* hb = (unsigned short*)alloc((size_t)n * 128 * 2);
    float* hmid   = (float*)alloc((size_t)n * 128 * 4);
    float* as1    = (float*)alloc((size_t)n * 8 * 4);
    float* ad1    = (float*)alloc((size_t)n * 8 * 4);
    float* as2    = (float*)alloc((size_t)n * 4);
    float* ad2    = (float*)alloc((size_t)n * 4);
    int*   cnt    = (int*)alloc((size_t)n * 4 * 2);
    int*   fillc  = cnt + n;
    int*   rowptr = (int*)alloc((size_t)(n + 1) * 4);
    int*   colsrc = (int*)alloc((size_t)en * 4);
    int*   bsum   = (int*)alloc((size_t)nb * 4);
    int*   bbase  = (int*)alloc((size_t)nb * 4);

    zero_kernel<<<(2 * n + 255) / 256, 256, 0, stream>>>(cnt, 2 * n);
    count_kernel<<<(en + 255) / 256, 256, 0, stream>>>(ei, e, n, cnt);
    scanA_kernel<<<nb, 256, 0, stream>>>(cnt, bsum, n);
    scanB_kernel<<<1, 64, 0, stream>>>(bsum, bbase, rowptr, nb, n);
    scanC_kernel<<<nb, 256, 0, stream>>>(cnt, bbase, rowptr, n);
    fill_kernel<<<(en + 255) / 256, 256, 0, stream>>>(ei, e, n, rowptr, fillc, colsrc);

    int gemm_grid = (n + 31) / 32;
    int node_grid = (n + 3) / 4;

    // layer 1
    gemm_alpha_kernel<8><<<gemm_grid, 256, 0, stream>>>(x, W1, a_s1, a_d1, hb, as1, ad1, n);
    agg_kernel<8><<<node_grid, 256, 0, stream>>>(rowptr, colsrc, hb, as1, ad1, b1, hmid, n, 1);

    // layer 2
    gemm_alpha_kernel<1><<<gemm_grid, 256, 0, stream>>>(hmid, W2, a_s2, a_d2, hb, as2, ad2, n);
    agg_kernel<1><<<node_grid, 256, 0, stream>>>(rowptr, colsrc, hb, as2, ad2, b2, (float*)d_out, n, 0);

    (void)n_in; (void)out_size; (void)ws_size;
}

// Round 7
// 191.455 us; speedup vs baseline: 1.1732x; 1.1732x over previous
//
#include <hip/hip_runtime.h>
#include <hip/hip_bf16.h>

#define NEG_SLOPE 0.2f

typedef short s16x8 __attribute__((ext_vector_type(8)));
typedef float f32x4 __attribute__((ext_vector_type(4)));

__device__ __forceinline__ unsigned short f2bf(float f) {
    unsigned int u = __float_as_uint(f);
    u += 0x7FFFu + ((u >> 16) & 1u);   // RNE
    return (unsigned short)(u >> 16);
}

// ---------------- CSR build ----------------

__global__ void zero_kernel(int* __restrict__ p, int count) {
    int i = blockIdx.x * blockDim.x + threadIdx.x;
    if (i < count) p[i] = 0;
}

__global__ void count_kernel(const int* __restrict__ ei, int e, int n, int* __restrict__ cnt) {
    int i = blockIdx.x * blockDim.x + threadIdx.x;
    int total = e + n;
    if (i >= total) return;
    int dst = (i < e) ? ei[e + i] : (i - e);
    atomicAdd(&cnt[dst], 1);
}

__global__ __launch_bounds__(256) void scanA_kernel(const int* __restrict__ cnt, int* __restrict__ bsum, int n) {
    int b = blockIdx.x, t = threadIdx.x;
    int base = b * 1024;
    int s = 0;
#pragma unroll
    for (int q = 0; q < 4; ++q) {
        int i = base + t + q * 256;
        if (i < n) s += cnt[i];
    }
    int lane = t & 63, wid = t >> 6;
#pragma unroll
    for (int off = 32; off; off >>= 1) s += __shfl_xor(s, off, 64);
    __shared__ int ws[4];
    if (lane == 0) ws[wid] = s;
    __syncthreads();
    if (t == 0) bsum[b] = ws[0] + ws[1] + ws[2] + ws[3];
}

__global__ __launch_bounds__(64) void scanB_kernel(const int* __restrict__ bsum, int* __restrict__ bbase,
                                                   int* __restrict__ rowptr, int nb, int n) {
    int t = threadIdx.x;
    int carry = 0;
    for (int c = 0; c < nb; c += 64) {
        int i = c + t;
        int v = (i < nb) ? bsum[i] : 0;
        int incl = v;
#pragma unroll
        for (int off = 1; off < 64; off <<= 1) {
            int u = __shfl_up(incl, off, 64);
            if (t >= off) incl += u;
        }
        if (i < nb) bbase[i] = carry + incl - v;
        carry += __shfl(incl, 63, 64);
    }
    if (t == 0) rowptr[n] = carry;
}

__global__ __launch_bounds__(256) void scanC_kernel(const int* __restrict__ cnt, const int* __restrict__ bbase,
                                                    int* __restrict__ rowptr, int n) {
    int b = blockIdx.x, t = threadIdx.x;
    int idx = b * 1024 + t * 4;
    int4 v = make_int4(0, 0, 0, 0);
    if (idx + 3 < n) v = *(const int4*)(cnt + idx);
    else {
        if (idx < n)     v.x = cnt[idx];
        if (idx + 1 < n) v.y = cnt[idx + 1];
        if (idx + 2 < n) v.z = cnt[idx + 2];
        if (idx + 3 < n) v.w = cnt[idx + 3];
    }
    int s0 = v.x, s1 = s0 + v.y, s2 = s1 + v.z, s3 = s2 + v.w;
    int tot = s3;
    int lane = t & 63, wid = t >> 6;
    int incl = tot;
#pragma unroll
    for (int off = 1; off < 64; off <<= 1) {
        int u = __shfl_up(incl, off, 64);
        if (lane >= off) incl += u;
    }
    __shared__ int wtot[4];
    if (lane == 63) wtot[wid] = incl;
    __syncthreads();
    int woff = 0;
    for (int w = 0; w < wid; ++w) woff += wtot[w];
    int ex = incl - tot + woff + bbase[b];
    if (idx < n)     rowptr[idx]     = ex;
    if (idx + 1 < n) rowptr[idx + 1] = ex + s0;
    if (idx + 2 < n) rowptr[idx + 2] = ex + s1;
    if (idx + 3 < n) rowptr[idx + 3] = ex + s2;
}

__global__ void fill_kernel(const int* __restrict__ ei, int e, int n,
                            const int* __restrict__ rowptr, int* __restrict__ fillc,
                            int* __restrict__ colsrc) {
    int i = blockIdx.x * blockDim.x + threadIdx.x;
    int total = e + n;
    if (i >= total) return;
    int src, dst;
    if (i < e) { src = ei[i]; dst = ei[e + i]; }
    else       { src = i - e; dst = i - e; }
    int pos = atomicAdd(&fillc[dst], 1);
    colsrc[rowptr[dst] + pos] = src;
}

// ---------------- prep: fragment-ordered bf16 [W | W@a] ----------------
// Wf[kt][ct][l][j] (kt=0..3, ct=0..8, l=0..63, j=0..7), flat ushort.
// ct<8 : B-frag of W col-tile ct: W[kt*32+(l>>4)*8+j][ct*16+(l&15)]
// ct==8: Wa columns. H=8: c=l&15: c<8 -> head c (asrc), c>=8 -> head c-8 (adst)
//        H=1: c==0 -> asrc dot, c==1 -> adst dot, else 0.

__global__ __launch_bounds__(256) void prep_w_kernel(const float* __restrict__ W,
                                                     const float* __restrict__ as_v,
                                                     const float* __restrict__ ad_v,
                                                     int H, unsigned short* __restrict__ Wf) {
    int kt = blockIdx.x;   // 0..3
    int t = threadIdx.x;
    for (int task = t; task < 9 * 64; task += 256) {
        int ct = task / 64, l = task & 63;
        int kbase = kt * 32 + (l >> 4) * 8;
        int c = l & 15;
        unsigned short o[8];
        if (ct < 8) {
            int col = ct * 16 + c;
#pragma unroll
            for (int j = 0; j < 8; ++j) o[j] = f2bf(W[(size_t)(kbase + j) * 128 + col]);
        } else {
#pragma unroll
            for (int j = 0; j < 8; ++j) {
                float s = 0.f;
                if (H == 8) {
                    const float* a = (c < 8) ? as_v : ad_v;
                    int hh = c & 7;
                    for (int m = 0; m < 16; ++m)
                        s += W[(size_t)(kbase + j) * 128 + hh * 16 + m] * a[hh * 16 + m];
                } else if (c < 2) {
                    const float* a = (c == 0) ? as_v : ad_v;
                    for (int m = 0; m < 128; ++m)
                        s += W[(size_t)(kbase + j) * 128 + m] * a[m];
                }
                o[j] = f2bf(s);
            }
        }
        *(uint4*)&Wf[(((size_t)kt * 9 + ct) * 64 + l) * 8] = *(uint4*)o;
    }
}

// ---------------- MFMA GEMM: [h | alpha] = X @ [W | Wa] ----------------
// block = 256 thr (4 waves), M-tile 64 (wave w -> rows w*16..+15), N = 144 (9 tiles).
// LDS: A frags 16KB + W frags 36KB = 52KB. One barrier.

template <int H, bool INBF16>
__global__ __launch_bounds__(256) void gemm_mfma_kernel(const void* __restrict__ Xv,
                                                        const unsigned short* __restrict__ Wf,
                                                        unsigned short* __restrict__ Ob,
                                                        float* __restrict__ as_out,
                                                        float* __restrict__ ad_out, int n) {
    __shared__ unsigned short lds[26624];   // 8192 A + 18432 W  (53248 B)
    int tid = threadIdx.x;
    int row0 = blockIdx.x * 64;

    // stage W frags: 2304 uint4, coalesced
    {
        const uint4* src = (const uint4*)Wf;
        uint4* dst = (uint4*)&lds[8192];
#pragma unroll
        for (int i = 0; i < 9; ++i) dst[tid + 256 * i] = src[tid + 256 * i];
    }
    // stage A frags: 1024 tasks; r=task>>4, kc=task&15 (coalesced 32B/thread reads)
#pragma unroll
    for (int q = 0; q < 4; ++q) {
        int task = tid + q * 256;
        int r = task >> 4, kc = task & 15;
        int gr = row0 + r;
        uint4 val = make_uint4(0, 0, 0, 0);
        if (gr < n) {
            if (INBF16) {
                val = *(const uint4*)((const unsigned short*)Xv + (size_t)gr * 128 + kc * 8);
            } else {
                const float4* xp = (const float4*)((const float*)Xv + (size_t)gr * 128 + kc * 8);
                float4 x0 = xp[0], x1 = xp[1];
                unsigned short o[8] = {f2bf(x0.x), f2bf(x0.y), f2bf(x0.z), f2bf(x0.w),
                                       f2bf(x1.x), f2bf(x1.y), f2bf(x1.z), f2bf(x1.w)};
                val = *(uint4*)o;
            }
        }
        int w = r >> 4, kt = kc >> 2, lane = ((kc & 3) << 4) + (r & 15);
        *(uint4*)&lds[(size_t)(((w * 4 + kt) * 64) + lane) * 8] = val;
    }
    __syncthreads();

    int w = tid >> 6, l = tid & 63;
    f32x4 acc[9];
#pragma unroll
    for (int ct = 0; ct < 9; ++ct) acc[ct] = (f32x4){0.f, 0.f, 0.f, 0.f};
#pragma unroll
    for (int kt = 0; kt < 4; ++kt) {
        s16x8 a = *(s16x8*)&lds[(size_t)((w * 4 + kt) * 64 + l) * 8];
#pragma unroll
        for (int ct = 0; ct < 9; ++ct) {
            s16x8 b = *(s16x8*)&lds[8192 + (size_t)((kt * 9 + ct) * 64 + l) * 8];
            acc[ct] = __builtin_amdgcn_mfma_f32_16x16x32_bf16(a, b, acc[ct], 0, 0, 0);
        }
    }

    // epilogue: C col = ct*16 + (l&15), row = w*16 + (l>>4)*4 + reg
    int c = l & 15, rgrp = l >> 4;
    int rowb = row0 + w * 16 + rgrp * 4;
#pragma unroll
    for (int reg = 0; reg < 4; ++reg) {
        int row = rowb + reg;
        if (row < n) {
#pragma unroll
            for (int ct = 0; ct < 8; ++ct)
                Ob[(size_t)row * 128 + ct * 16 + c] = f2bf(acc[ct][reg]);
            float av = acc[8][reg];
            if (H == 8) {
                if (c < 8) as_out[(size_t)row * 8 + c] = av;
                else       ad_out[(size_t)row * 8 + (c - 8)] = av;
            } else {
                if (c == 0)      as_out[row] = av;
                else if (c == 1) ad_out[row] = av;
            }
        }
    }
}

// ---------------- single-pass aggregation, bf16 gather ----------------
// wave per node; slot = lane>>4 (4 edges), cl = lane&15 (8 ch = 16 B/lane)
// OBF: write bf16 (+ELU) for layer-1 output; else fp32.

template <int H, int OBF>
__global__ __launch_bounds__(256) void agg_kernel(const int* __restrict__ rowptr,
                                                  const int* __restrict__ colsrc,
                                                  const unsigned short* __restrict__ hb,
                                                  const float* __restrict__ as,
                                                  const float* __restrict__ ad,
                                                  const float* __restrict__ bias,
                                                  void* __restrict__ outv, int n) {
    int node = blockIdx.x * 4 + (threadIdx.x >> 6);
    int lane = threadIdx.x & 63;
    if (node >= n) return;
    int beg = rowptr[node];
    int end = rowptr[node + 1];

    int slot = lane >> 4;
    int cl = lane & 15;
    int head = (H == 8) ? (cl >> 1) : 0;
    float adh = ad[(size_t)node * H + head];

    float acc[8];
#pragma unroll
    for (int c = 0; c < 8; ++c) acc[c] = 0.f;
    float den = 0.f;

#pragma unroll 2
    for (int i = beg + slot; i < end; i += 4) {
        int s = colsrc[i];
        float ev = as[(size_t)s * H + head] + adh;
        ev = (ev > 0.f) ? ev : NEG_SLOPE * ev;
        float wgt = __expf(ev);
        den += wgt;
        uint4 a = *(const uint4*)(hb + (size_t)s * 128 + cl * 8);
        unsigned int u[4] = {a.x, a.y, a.z, a.w};
#pragma unroll
        for (int k = 0; k < 4; ++k) {
            float lo = __uint_as_float(u[k] << 16);
            float hi = __uint_as_float(u[k] & 0xffff0000u);
            acc[2 * k]     += wgt * lo;
            acc[2 * k + 1] += wgt * hi;
        }
    }

#pragma unroll
    for (int off = 16; off <= 32; off <<= 1) {
        den += __shfl_xor(den, off, 64);
#pragma unroll
        for (int c = 0; c < 8; ++c) acc[c] += __shfl_xor(acc[c], off, 64);
    }

    if (slot == 0) {
        float inv = 1.0f / den;
        float r[8];
#pragma unroll
        for (int k = 0; k < 8; ++k) {
            float bb = bias[cl * 8 + k];
            r[k] = acc[k] * inv + bb;
            if (OBF) r[k] = (r[k] > 0.f) ? r[k] : expm1f(r[k]);  // ELU (layer 1)
        }
        if (OBF) {
            unsigned short o[8];
#pragma unroll
            for (int k = 0; k < 8; ++k) o[k] = f2bf(r[k]);
            *(uint4*)((unsigned short*)outv + (size_t)node * 128 + cl * 8) = *(uint4*)o;
        } else {
            float4 r0 = make_float4(r[0], r[1], r[2], r[3]);
            float4 r1 = make_float4(r[4], r[5], r[6], r[7]);
            float4* p = (float4*)((float*)outv + (size_t)node * 128 + cl * 8);
            p[0] = r0; p[1] = r1;
        }
    }
}

// ---------------- launch ----------------

extern "C" void kernel_launch(void* const* d_in, const int* in_sizes, int n_in,
                              void* d_out, int out_size, void* d_ws, size_t ws_size,
                              hipStream_t stream) {
    const float* x    = (const float*)d_in[0];
    const int*   ei   = (const int*)d_in[1];
    const float* W1   = (const float*)d_in[2];
    const float* a_s1 = (const float*)d_in[3];
    const float* a_d1 = (const float*)d_in[4];
    const float* b1   = (const float*)d_in[5];
    const float* W2   = (const float*)d_in[6];
    const float* a_s2 = (const float*)d_in[7];
    const float* a_d2 = (const float*)d_in[8];
    const float* b2   = (const float*)d_in[9];

    const int n  = in_sizes[0] / 128;
    const int e  = in_sizes[1] / 2;
    const int en = e + n;
    const int nb = (n + 1023) / 1024;

    char* ws = (char*)d_ws;
    size_t off = 0;
    auto alloc = [&](size_t bytes) -> void* {
        void* p = ws + off;
        off += (bytes + 255) & ~(size_t)255;
        return p;
    };
    unsigned short* hb   = (unsigned short*)alloc((size_t)n * 128 * 2);  // bf16 h (both layers)
    unsigned short* hmid = (unsigned short*)alloc((size_t)n * 128 * 2);  // bf16 ELU(layer1)
    float* as1    = (float*)alloc((size_t)n * 8 * 4);
    float* ad1    = (float*)alloc((size_t)n * 8 * 4);
    float* as2    = (float*)alloc((size_t)n * 4);
    float* ad2    = (float*)alloc((size_t)n * 4);
    int*   cnt    = (int*)alloc((size_t)n * 4 * 2);
    int*   fillc  = cnt + n;
    int*   rowptr = (int*)alloc((size_t)(n + 1) * 4);
    int*   colsrc = (int*)alloc((size_t)en * 4);
    int*   bsum   = (int*)alloc((size_t)nb * 4);
    int*   bbase  = (int*)alloc((size_t)nb * 4);
    unsigned short* Wf1 = (unsigned short*)alloc(4 * 9 * 64 * 8 * 2);
    unsigned short* Wf2 = (unsigned short*)alloc(4 * 9 * 64 * 8 * 2);

    // CSR build (same graph both layers)
    zero_kernel<<<(2 * n + 255) / 256, 256, 0, stream>>>(cnt, 2 * n);
    count_kernel<<<(en + 255) / 256, 256, 0, stream>>>(ei, e, n, cnt);
    scanA_kernel<<<nb, 256, 0, stream>>>(cnt, bsum, n);
    scanB_kernel<<<1, 64, 0, stream>>>(bsum, bbase, rowptr, nb, n);
    scanC_kernel<<<nb, 256, 0, stream>>>(cnt, bbase, rowptr, n);
    fill_kernel<<<(en + 255) / 256, 256, 0, stream>>>(ei, e, n, rowptr, fillc, colsrc);

    // weight prep (fragment-ordered bf16 [W | W@a])
    prep_w_kernel<<<4, 256, 0, stream>>>(W1, a_s1, a_d1, 8, Wf1);
    prep_w_kernel<<<4, 256, 0, stream>>>(W2, a_s2, a_d2, 1, Wf2);

    int gemm_grid = (n + 63) / 64;
    int node_grid = (n + 3) / 4;

    // layer 1
    gemm_mfma_kernel<8, false><<<gemm_grid, 256, 0, stream>>>(x, Wf1, hb, as1, ad1, n);
    agg_kernel<8, 1><<<node_grid, 256, 0, stream>>>(rowptr, colsrc, hb, as1, ad1, b1, hmid, n);

    // layer 2
    gemm_mfma_kernel<1, true><<<gemm_grid, 256, 0, stream>>>(hmid, Wf2, hb, as2, ad2, n);
    agg_kernel<1, 0><<<node_grid, 256, 0, stream>>>(rowptr, colsrc, hb, as2, ad2, b2, d_out, n);

    (void)n_in; (void)out_size; (void)ws_size;
}